// Round 10
// baseline (212.230 us; speedup 1.0000x reference)
//
#include <hip/hip_runtime.h>
#include <math.h>

#define BB 2
#define TT 2048
#define DD 1024
#define NH 16
#define NKV 4
#define HD 64
#define EPSF 1.1920929e-07f
// T=2048 > TSL=1024 -> nb = 10000 * 2^(64/62); log2(nb) = log2(1e4) + 64/62
#define LOG2_NB 14.319970444065578
// 0.125 (1/sqrt(64)) * log2(e): folded into q so softmax runs in exp2 domain
#define SCALE_LOG2E 0.18033688011112042f
// fixed softmax max (exp2 units): |q.k| <= 8*8*1.5*0.125*log2e = 17.31 < 17.5
#define FIXMAX 17.5f
#define INV2PI 0.15915494309189535f

typedef __attribute__((ext_vector_type(8))) short bf16x8;
typedef __attribute__((ext_vector_type(4))) float f32x4;

__device__ inline short f2bf(float f) {
    unsigned u = __builtin_bit_cast(unsigned, f);
    unsigned r = (u + 0x7fffu + ((u >> 16) & 1u)) >> 16;
    return (short)r;
}
// packed f32x2 -> bf16x2 (hardware RNE rounding, 1 VALU op)
__device__ inline unsigned cvt_pk_bf16(float a, float b) {
    unsigned r;
    asm("v_cvt_pk_bf16_f32 %0, %1, %2" : "=v"(r) : "v"(a), "v"(b));
    return r;
}
__device__ inline float hw_sin(float rev) {
    float r; asm("v_sin_f32 %0, %1" : "=v"(r) : "v"(rev)); return r;
}
__device__ inline float hw_cos(float rev) {
    float r; asm("v_cos_f32 %0, %1" : "=v"(r) : "v"(rev)); return r;
}

// ---------------- fp32 -> bf16 conversion for the 4 weight tensors ----------------
__global__ __launch_bounds__(256) void conv_w(
    const float* __restrict__ qw, const float* __restrict__ kw,
    const float* __restrict__ vw, const float* __restrict__ ow,
    short* __restrict__ wb16, short* __restrict__ ow16)
{
    int i = blockIdx.x * 256 + threadIdx.x;   // float4 index, total 655360
    const float* src; short* dst; int j;
    if (i < 262144)      { src = qw; dst = wb16;           j = i; }
    else if (i < 327680) { src = kw; dst = wb16 + 1048576; j = i - 262144; }
    else if (i < 393216) { src = vw; dst = wb16 + 1310720; j = i - 327680; }
    else                 { src = ow; dst = ow16;           j = i - 393216; }
    float4 v = ((const float4*)src)[j];
    short4 o;
    o.x = f2bf(v.x); o.y = f2bf(v.y); o.z = f2bf(v.z); o.w = f2bf(v.w);
    ((short4*)dst)[j] = o;
}

// ---------------- bf16 MFMA GEMM: C = A * B^T over K range [z*klen, (z+1)*klen) ----------------
// 128x128 tile, BK=32, 256 threads = 4 waves. LDS frag reads -> prefetch DMA -> MFMA -> barrier.
__global__ __launch_bounds__(256, 4) void gemm_mfma(
    const short* __restrict__ A, const short* __restrict__ Bmat,
    float* __restrict__ C, int ldc, int klen)
{
    __shared__ short As[2][128*32];
    __shared__ short Bs[2][128*32];
    int tid = threadIdx.x;
    int w = tid >> 6, lane = tid & 63;
    int quad = lane >> 4, lc = lane & 15;
    int wy = w >> 1, wx = w & 1;
    int m0 = blockIdx.y * 128, n0 = blockIdx.x * 128;
    int kbeg = blockIdx.z * klen, kend = kbeg + klen;
    float* Cz = C + (size_t)blockIdx.z * 4096 * ldc;

    f32x4 acc[4][4];
    #pragma unroll
    for (int i = 0; i < 4; i++)
        #pragma unroll
        for (int j = 0; j < 4; j++) acc[i][j] = (f32x4){0.f,0.f,0.f,0.f};

    #define GSTAGE(buf, k0)                                                             \
    {                                                                                   \
        _Pragma("unroll")                                                               \
        for (int i = 0; i < 2; i++) {                                                   \
            int off = w*2048 + i*1024;            /* byte offset, wave-uniform */       \
            int g = (off >> 4) + lane;            /* 16B chunk idx */                   \
            int row = g >> 2, c = g & 3;                                                \
            int cg = c ^ (row & 3);               /* XOR swizzle */                     \
            const short* ga = A + (size_t)(m0 + row)*1024 + (k0) + cg*8;                \
            __builtin_amdgcn_global_load_lds(                                           \
                (const __attribute__((address_space(1))) void*)ga,                      \
                (__attribute__((address_space(3))) void*)((char*)&As[buf][0] + off), 16, 0, 0); \
            const short* gb = Bmat + (size_t)(n0 + row)*1024 + (k0) + cg*8;             \
            __builtin_amdgcn_global_load_lds(                                           \
                (const __attribute__((address_space(1))) void*)gb,                      \
                (__attribute__((address_space(3))) void*)((char*)&Bs[buf][0] + off), 16, 0, 0); \
        }                                                                               \
    }

    GSTAGE(0, kbeg);
    __syncthreads();

    for (int k0 = kbeg; k0 < kend; k0 += 32) {
        int cur = ((k0 - kbeg) >> 5) & 1;
        bf16x8 af[4], bfr[4];
        #pragma unroll
        for (int tm = 0; tm < 4; tm++) {
            int row = wy*64 + tm*16 + lc;
            af[tm] = *(const bf16x8*)(&As[cur][0] + row*32 + ((quad*8) ^ ((row&3)*8)));
        }
        #pragma unroll
        for (int tn = 0; tn < 4; tn++) {
            int row = wx*64 + tn*16 + lc;
            bfr[tn] = *(const bf16x8*)(&Bs[cur][0] + row*32 + ((quad*8) ^ ((row&3)*8)));
        }
        if (k0 + 32 < kend) GSTAGE(cur ^ 1, k0 + 32);
        #pragma unroll
        for (int tm = 0; tm < 4; tm++)
            #pragma unroll
            for (int tn = 0; tn < 4; tn++)
                acc[tm][tn] = __builtin_amdgcn_mfma_f32_16x16x32_bf16(af[tm], bfr[tn], acc[tm][tn], 0, 0, 0);
        __syncthreads();
    }

    #pragma unroll
    for (int tm = 0; tm < 4; tm++)
        #pragma unroll
        for (int r = 0; r < 4; r++) {
            int m = m0 + wy*64 + tm*16 + quad*4 + r;
            #pragma unroll
            for (int tn = 0; tn < 4; tn++) {
                int n = n0 + wx*64 + tn*16 + lc;
                Cz[(size_t)m*ldc + n] = acc[tm][tn][r];
            }
        }
}

// ---------------- out-proj GEMM: 128x64 tile (512 blocks for occupancy), K=1024 ----------------
__global__ __launch_bounds__(256, 4) void gemm_out_mfma(
    const short* __restrict__ A, const short* __restrict__ Bmat, float* __restrict__ C)
{
    __shared__ short As[2][128*32];
    __shared__ short Bs[2][64*32];
    int tid = threadIdx.x;
    int w = tid >> 6, lane = tid & 63;
    int quad = lane >> 4, lc = lane & 15;
    int m0 = blockIdx.y * 128, n0 = blockIdx.x * 64;

    f32x4 acc[2][4];
    #pragma unroll
    for (int i = 0; i < 2; i++)
        #pragma unroll
        for (int j = 0; j < 4; j++) acc[i][j] = (f32x4){0.f,0.f,0.f,0.f};

    #define OSTAGE(buf, k0)                                                             \
    {                                                                                   \
        _Pragma("unroll")                                                               \
        for (int i = 0; i < 2; i++) {                                                   \
            int off = w*2048 + i*1024;                                                  \
            int g = (off >> 4) + lane;                                                  \
            int row = g >> 2, c = g & 3;                                                \
            int cg = c ^ (row & 3);                                                     \
            const short* ga = A + (size_t)(m0 + row)*1024 + (k0) + cg*8;                \
            __builtin_amdgcn_global_load_lds(                                           \
                (const __attribute__((address_space(1))) void*)ga,                      \
                (__attribute__((address_space(3))) void*)((char*)&As[buf][0] + off), 16, 0, 0); \
        }                                                                               \
        {                                                                               \
            int off = w*1024;                                                           \
            int g = (off >> 4) + lane;                                                  \
            int row = g >> 2, c = g & 3;                                                \
            int cg = c ^ (row & 3);                                                     \
            const short* gb = Bmat + (size_t)(n0 + row)*1024 + (k0) + cg*8;             \
            __builtin_amdgcn_global_load_lds(                                           \
                (const __attribute__((address_space(1))) void*)gb,                      \
                (__attribute__((address_space(3))) void*)((char*)&Bs[buf][0] + off), 16, 0, 0); \
        }                                                                               \
    }

    OSTAGE(0, 0);
    __syncthreads();

    for (int k0 = 0; k0 < 1024; k0 += 32) {
        int cur = (k0 >> 5) & 1;
        bf16x8 af[2], bfr[4];
        #pragma unroll
        for (int tm = 0; tm < 2; tm++) {
            int row = w*32 + tm*16 + lc;
            af[tm] = *(const bf16x8*)(&As[cur][0] + row*32 + ((quad*8) ^ ((row&3)*8)));
        }
        #pragma unroll
        for (int tn = 0; tn < 4; tn++) {
            int row = tn*16 + lc;
            bfr[tn] = *(const bf16x8*)(&Bs[cur][0] + row*32 + ((quad*8) ^ ((row&3)*8)));
        }
        if (k0 + 32 < 1024) OSTAGE(cur ^ 1, k0 + 32);
        #pragma unroll
        for (int tm = 0; tm < 2; tm++)
            #pragma unroll
            for (int tn = 0; tn < 4; tn++)
                acc[tm][tn] = __builtin_amdgcn_mfma_f32_16x16x32_bf16(af[tm], bfr[tn], acc[tm][tn], 0, 0, 0);
        __syncthreads();
    }

    #pragma unroll
    for (int tm = 0; tm < 2; tm++)
        #pragma unroll
        for (int r = 0; r < 4; r++) {
            int m = m0 + w*32 + tm*16 + quad*4 + r;
            #pragma unroll
            for (int tn = 0; tn < 4; tn++)
                C[(size_t)m*1024 + n0 + tn*16 + lc] = acc[tm][tn][r];
        }
}

// ---------------- epilogue: sum split-K partials; RMSNorm + RoPE (HW sin/cos) + gain*scale ----------------
__global__ __launch_bounds__(256) void qkv_epilogue(
    const float* __restrict__ qp0, const float* __restrict__ qp1,
    const float* __restrict__ ve, const float* __restrict__ v0,
    const float* __restrict__ q_gain, const float* __restrict__ vr_lambda,
    short* __restrict__ qbh, short* __restrict__ kbh, short* __restrict__ vb,
    float* __restrict__ rawv)
{
    int wave = blockIdx.x * 4 + (threadIdx.x >> 6);
    int lane = threadIdx.x & 63;
    int row = wave / 24;     // 0..4095  (b*T + t)
    int hh  = wave % 24;
    int b = row >> 11;
    int t = row & (TT - 1);

    if (hh < 20) {
        int col = (hh < 16) ? (hh*64 + lane) : (1024 + (hh-16)*64 + lane);
        size_t idx = (size_t)row*1536 + col;
        float val = qp0[idx] + qp1[idx];
        float ss = val * val;
        #pragma unroll
        for (int off = 32; off; off >>= 1) ss += __shfl_xor(ss, off);
        val *= rsqrtf(ss * (1.0f/64.0f) + EPSF);
        float partner = __shfl(val, lane ^ 32);
        int idxr = lane & 31;
        float inv = (float)exp2((double)idxr * (-LOG2_NB / 32.0));
        float fr = (float)t * inv;
        float rev = fr * INV2PI;
        rev = rev - floorf(rev);
        float sn = hw_sin(rev), cs = hw_cos(rev);
        float outv = (lane < 32) ? (val*cs + partner*sn) : (val*cs - partner*sn);
        if (hh < 16) {
            outv *= q_gain[hh] * SCALE_LOG2E;    // fold softmax scale+log2e into q
            qbh[(((size_t)(b*16 + hh))*2048 + t)*64 + lane] = f2bf(outv);
        } else {
            kbh[(((size_t)(b*4 + (hh-16)))*2048 + t)*64 + lane] = f2bf(outv);
        }
    } else {
        int vh = hh - 20;
        size_t off = ((size_t)row*4 + vh)*64 + lane;
        size_t idx = (size_t)row*1536 + 1280 + vh*64 + lane;
        float vraw = qp0[idx] + qp1[idx] + ve[off];
        rawv[off] = vraw;
        float vmix = vr_lambda[0]*v0[off] + vr_lambda[1]*vraw;
        vb[off] = f2bf(vmix);                    // coalesced [b][t][kvh][d]
    }
}

// ---------------- V transpose: vb [b][t][kvh][d] -> vtb [b*4+kvh][d][t] ----------------
__global__ __launch_bounds__(256) void transpose_v(
    const short* __restrict__ vb, short* __restrict__ vtb)
{
    __shared__ short tile[64][72];
    int bk = blockIdx.x;           // b*4+kvh
    int tt = blockIdx.y;           // t tile (64)
    int b = bk >> 2, kvh = bk & 3;
    int tid = threadIdx.x;
    int t4 = tid >> 4;             // 0..15
    int d4 = (tid & 15) * 4;       // 0..60
    #pragma unroll
    for (int i = 0; i < 4; i++) {
        int t = t4 + i*16;
        const short* src = vb + (((size_t)(b*2048 + tt*64 + t)*4 + kvh)*64 + d4);
        *(short4*)&tile[t][d4] = *(const short4*)src;
    }
    __syncthreads();
    #pragma unroll
    for (int i = 0; i < 4; i++) {
        int d = t4 + i*16;
        int t0 = d4;
        short4 o;
        o.x = tile[t0+0][d]; o.y = tile[t0+1][d];
        o.z = tile[t0+2][d]; o.w = tile[t0+3][d];
        *(short4*)&vtb[((size_t)(bk*64 + d))*2048 + tt*64 + t0] = o;
    }
}

// ---------------- gate + x->bf16: sigmoid(x @ gate_w.T + gate_b), also emits x16 ----------------
__global__ __launch_bounds__(256) void gate_kernel(
    const float* __restrict__ x, const float* __restrict__ gw,
    const float* __restrict__ gb, float* __restrict__ gate, short* __restrict__ x16)
{
    __shared__ float xs[1024];
    int row = blockIdx.x;
    int tid = threadIdx.x;
    float4 xv = *(const float4*)&x[(size_t)row*1024 + tid*4];
    *(float4*)&xs[tid*4] = xv;
    short4 xo;
    xo.x = f2bf(xv.x); xo.y = f2bf(xv.y); xo.z = f2bf(xv.z); xo.w = f2bf(xv.w);
    ((short4*)(x16 + (size_t)row*1024))[tid] = xo;
    __syncthreads();
    int wave = tid >> 6, lane = tid & 63;
    for (int h = wave; h < 16; h += 4) {
        const float* w = gw + (size_t)h * 1024;
        float s = 0.f;
        #pragma unroll
        for (int i = 0; i < 16; i++) s += xs[lane + 64*i] * w[lane + 64*i];
        #pragma unroll
        for (int off = 32; off; off >>= 1) s += __shfl_xor(s, off);
        if (lane == 0) gate[(size_t)row*16 + h] = 1.0f / (1.0f + __expf(-(s + gb[h])));
    }
}

// ---------------- MFMA flash attention v5: 128-q tiles (halved LDS traffic per unit work) ----------------
__global__ __launch_bounds__(256, 2) void flash_mfma(
    const short* __restrict__ qbh, const short* __restrict__ kbh,
    const short* __restrict__ vtb, const float* __restrict__ gate,
    short* __restrict__ y16)
{
    __shared__ short Ks[2][64*64];
    __shared__ short Vt[2][64*64];
    __shared__ short Ps[4][32*64];   // per wave: 32 q rows x 64 keys; 8B-chunk XOR swizzle

    int bh = blockIdx.x;             // b*16 + h
    int b = bh >> 4, h = bh & 15, kvh = h >> 2;
    int qt = 15 - blockIdx.y;        // 128-row q tile; long blocks launch first
    int tid = threadIdx.x;
    int w = tid >> 6, lane = tid & 63;
    int quad = lane >> 4, lc = lane & 15;

    bf16x8 qf[2][2];
    #pragma unroll
    for (int qg = 0; qg < 2; qg++) {
        const short* qbase = qbh + (((size_t)bh)*2048 + qt*128 + w*32 + qg*16 + lc)*64;
        qf[qg][0] = *(const bf16x8*)(qbase + quad*8);
        qf[qg][1] = *(const bf16x8*)(qbase + 32 + quad*8);
    }

    f32x4 o[2][4];
    f32x4 l4[2];
    #pragma unroll
    for (int qg = 0; qg < 2; qg++) {
        l4[qg] = (f32x4){0.f,0.f,0.f,0.f};
        #pragma unroll
        for (int i = 0; i < 4; i++) o[qg][i] = (f32x4){0.f,0.f,0.f,0.f};
    }
    const bf16x8 ones = {(short)0x3F80,(short)0x3F80,(short)0x3F80,(short)0x3F80,
                         (short)0x3F80,(short)0x3F80,(short)0x3F80,(short)0x3F80};

    const size_t kbase = ((size_t)(b*4 + kvh))*2048*64;   // K [t][d]
    const size_t vbase = ((size_t)(b*4 + kvh))*64*2048;   // V^T [d][t]

    #define STAGE(buf, kt)                                                              \
    {                                                                                   \
        _Pragma("unroll")                                                               \
        for (int i = 0; i < 2; i++) {                                                   \
            int off = w*2048 + i*1024;                                                  \
            int g = (off >> 4) + lane;                                                  \
            int row = g >> 3, c = g & 7;                                                \
            int cg = c ^ (row & 7);                                                     \
            const short* gk = kbh + kbase + (size_t)((kt)*64 + row)*64 + cg*8;          \
            __builtin_amdgcn_global_load_lds(                                           \
                (const __attribute__((address_space(1))) void*)gk,                      \
                (__attribute__((address_space(3))) void*)((char*)Ks[buf] + off), 16, 0, 0); \
            const short* gv = vtb + vbase + (size_t)row*2048 + (kt)*64 + cg*8;          \
            __builtin_amdgcn_global_load_lds(                                           \
                (const __attribute__((address_space(1))) void*)gv,                      \
                (__attribute__((address_space(3))) void*)((char*)Vt[buf] + off), 16, 0, 0); \
        }                                                                               \
    }

    STAGE(0, 0);
    __syncthreads();

    short* ps = Ps[w];
    int nkt = 2*qt + 2;
    int qmax_w = qt*128 + w*32 + 31;

    for (int kt = 0; kt < nkt; kt++) {
        int cur = kt & 1;
        bool live = (kt*64 <= qmax_w);   // wave-uniform

        bf16x8 kf0[4], kf1[4], vf0[4], vf1[4];
        if (live) {
            #pragma unroll
            for (int kn = 0; kn < 4; kn++) {
                int row = kn*16 + lc;
                int sw = (row & 7) * 8;
                const short* kr = Ks[cur] + row*64;
                kf0[kn] = *(const bf16x8*)(kr + ((quad*8) ^ sw));
                kf1[kn] = *(const bf16x8*)(kr + ((quad*8 + 32) ^ sw));
                const short* vr = Vt[cur] + row*64;
                vf0[kn] = *(const bf16x8*)(vr + ((quad*8) ^ sw));
                vf1[kn] = *(const bf16x8*)(vr + ((quad*8 + 32) ^ sw));
            }
        }
        if (kt + 1 < nkt) STAGE(cur ^ 1, kt + 1);

        if (live) {
            #pragma unroll
            for (int qg = 0; qg < 2; qg++) {
                f32x4 s4[4];
                #pragma unroll
                for (int kn = 0; kn < 4; kn++) {
                    f32x4 acc = (f32x4){0.f,0.f,0.f,0.f};
                    acc = __builtin_amdgcn_mfma_f32_16x16x32_bf16(kf0[kn], qf[qg][0], acc, 0, 0, 0);
                    acc = __builtin_amdgcn_mfma_f32_16x16x32_bf16(kf1[kn], qf[qg][1], acc, 0, 0, 0);
                    s4[kn] = acc;
                }
                bool diag = (kt*64 + 63 > qt*128 + w*32 + qg*16);   // wave-uniform
                int qv = qt*128 + w*32 + qg*16 + lc;
                #pragma unroll
                for (int kn = 0; kn < 4; kn++) {
                    float p0 = __builtin_amdgcn_exp2f(s4[kn][0] - FIXMAX);
                    float p1 = __builtin_amdgcn_exp2f(s4[kn][1] - FIXMAX);
                    float p2 = __builtin_amdgcn_exp2f(s4[kn][2] - FIXMAX);
                    float p3 = __builtin_amdgcn_exp2f(s4[kn][3] - FIXMAX);
                    if (diag) {
                        int keyb = kt*64 + kn*16 + quad*4;
                        if (keyb + 0 > qv) p0 = 0.f;
                        if (keyb + 1 > qv) p1 = 0.f;
                        if (keyb + 2 > qv) p2 = 0.f;
                        if (keyb + 3 > qv) p3 = 0.f;
                    }
                    int c = kn*4 + quad;
                    int cs = c ^ ((lc & 7) << 1);
                    int2 pk;
                    pk.x = (int)cvt_pk_bf16(p0, p1);
                    pk.y = (int)cvt_pk_bf16(p2, p3);
                    *(int2*)(ps + (qg*16 + lc)*64 + cs*4) = pk;
                }
            }
            __asm__ volatile("s_waitcnt lgkmcnt(0)" ::: "memory");
            #pragma unroll
            for (int qg = 0; qg < 2; qg++) {
                int u0 = quad ^ (lc & 7);
                int u1 = (4 + quad) ^ (lc & 7);
                bf16x8 pf0 = *(const bf16x8*)(ps + (qg*16 + lc)*64 + u0*8);
                bf16x8 pf1 = *(const bf16x8*)(ps + (qg*16 + lc)*64 + u1*8);
                #pragma unroll
                for (int dn = 0; dn < 4; dn++) {
                    o[qg][dn] = __builtin_amdgcn_mfma_f32_16x16x32_bf16(pf0, vf0[dn], o[qg][dn], 0, 0, 0);
                    o[qg][dn] = __builtin_amdgcn_mfma_f32_16x16x32_bf16(pf1, vf1[dn], o[qg][dn], 0, 0, 0);
                }
                l4[qg] = __builtin_amdgcn_mfma_f32_16x16x32_bf16(pf0, ones, l4[qg], 0, 0, 0);
                l4[qg] = __builtin_amdgcn_mfma_f32_16x16x32_bf16(pf1, ones, l4[qg], 0, 0, 0);
            }
        }
        __syncthreads();
    }

    #pragma unroll
    for (int qg = 0; qg < 2; qg++)
        #pragma unroll
        for (int r = 0; r < 4; r++) {
            int row = b*2048 + qt*128 + w*32 + qg*16 + quad*4 + r;
            float g = gate[(size_t)row*16 + h] / l4[qg][r];
            #pragma unroll
            for (int dn = 0; dn < 4; dn++)
                y16[(size_t)row*1024 + h*64 + dn*16 + lc] = f2bf(o[qg][dn][r] * g);
        }
}

extern "C" void kernel_launch(void* const* d_in, const int* in_sizes, int n_in,
                              void* d_out, int out_size, void* d_ws, size_t ws_size,
                              hipStream_t stream) {
    (void)in_sizes; (void)n_in; (void)out_size; (void)ws_size;
    const float* x  = (const float*)d_in[0];
    const float* qw = (const float*)d_in[1];
    const float* kw = (const float*)d_in[2];
    const float* vw = (const float*)d_in[3];
    const float* ow = (const float*)d_in[4];
    const float* ve = (const float*)d_in[5];
    const float* v0 = (const float*)d_in[6];
    const float* qg = (const float*)d_in[7];
    const float* vl = (const float*)d_in[8];
    const float* gw = (const float*)d_in[9];
    const float* gb = (const float*)d_in[10];

    float* out  = (float*)d_out;
    float* rawv = out + (size_t)BB*TT*DD;

    // workspace layout (float units)
    float* ws   = (float*)d_ws;
    float* qkvp = ws;                               // 2 x 4096*1536 f32 split-K partials
    float* p    = ws + 2*6291456;
    short* x16  = (short*)p;        p += 2097152;   // 4096*1024 bf16
    short* wb16 = (short*)p;        p += 786432;    // 1536*1024 bf16 (qw|kw|vw)
    short* ow16 = (short*)p;        p += 524288;    // 1024*1024 bf16
    short* qbh  = (short*)p;        p += 2097152;   // [b*16+h][t][d] bf16
    short* kbh  = (short*)p;        p += 524288;    // [b*4+kvh][t][d] bf16
    short* vtb  = (short*)p;        p += 524288;    // [b*4+kvh][d][t] bf16
    short* vb   = (short*)p;        p += 524288;    // [b][t][kvh][d] bf16 (pre-transpose)
    float* gt   = p;                                // 4096*16 f32
    short* y16  = (short*)qkvp;                     // reuses partial region post-epilogue

    conv_w<<<2560, 256, 0, stream>>>(qw, kw, vw, ow, wb16, ow16);
    gate_kernel<<<4096, 256, 0, stream>>>(x, gw, gb, gt, x16);
    // QKV projection: M=4096, N=1536, split-K=2 (z-dim), partials -> qkvp[z]
    gemm_mfma<<<dim3(12, 32, 2), 256, 0, stream>>>(x16, wb16, qkvp, 1536, 512);
    qkv_epilogue<<<24576, 256, 0, stream>>>(qkvp, qkvp + 6291456, ve, v0, qg, vl,
                                            qbh, kbh, vb, rawv);
    transpose_v<<<dim3(8, 32), 256, 0, stream>>>(vb, vtb);
    flash_mfma<<<dim3(32, 16), 256, 0, stream>>>(qbh, kbh, vtb, gt, y16);
    // out projection: M=4096, N=1024, 128x64 tiles
    gemm_out_mfma<<<dim3(16, 32), 256, 0, stream>>>(y16, ow16, out);
}